// Round 3
// baseline (3065.482 us; speedup 1.0000x reference)
//
#include <hip/hip_runtime.h>

typedef __bf16 bf16x8 __attribute__((ext_vector_type(8)));
typedef float floatx4 __attribute__((ext_vector_type(4)));

#define MFMA(a, b, c) __builtin_amdgcn_mfma_f32_16x16x32_bf16((a), (b), (c), 0, 0, 0)

__device__ __forceinline__ float bf2f(ushort u) {
    union { unsigned int i; float f; } v; v.i = ((unsigned int)u) << 16; return v.f;
}
__device__ __forceinline__ ushort f2bf(float f) {
    union { float f; unsigned int i; } v; v.f = f;
    unsigned int r = v.i + 0x7fffu + ((v.i >> 16) & 1u);
    return (ushort)(r >> 16);
}
__device__ __forceinline__ bf16x8 ldb8(const ushort* p) { return *(const bf16x8*)p; }

// ---------------------------------------------------------------- fp32 -> bf16 transpose
__global__ __launch_bounds__(256) void transpose_f32_bf16(
    const float* __restrict__ in, ushort* __restrict__ out, int R, int C) {
    __shared__ ushort tile[32][33];
    const int c0 = blockIdx.x * 32, r0 = blockIdx.y * 32;
    const int tx = threadIdx.x, ty = threadIdx.y;
    #pragma unroll
    for (int i = 0; i < 32; i += 8) {
        int r = r0 + ty + i, c = c0 + tx;
        if (r < R && c < C) tile[ty + i][tx] = f2bf(in[(long)r * C + c]);
    }
    __syncthreads();
    #pragma unroll
    for (int i = 0; i < 32; i += 8) {
        int r = c0 + ty + i, c = r0 + tx;   // out is C x R
        if (r < C && c < R) out[(long)r * R + c] = tile[tx][ty + i];
    }
}

// ---------------------------------------------------------------- fp32 -> bf16 elementwise (n % 4 == 0)
__global__ __launch_bounds__(256) void cvt_f32_bf16(
    const float* __restrict__ in, ushort* __restrict__ out, long n) {
    const long i = ((long)blockIdx.x * 256 + threadIdx.x) * 4;
    if (i >= n) return;
    float4 v = *(const float4*)(in + i);
    ushort4 o;
    o.x = f2bf(v.x); o.y = f2bf(v.y); o.z = f2bf(v.z); o.w = f2bf(v.w);
    *(ushort4*)(out + i) = o;
}

// ---------------------------------------------------------------- GEMM C = A * B^T (bf16 in; bf16 or fp32 out)
// A: (M x K) bf16 row-major, lda; Bt: (N x K) bf16 row-major, ldb; C: (M x N), ldc.
// Per-z offsets for head batching. Tile 64x64, BK=64, 4 waves in 2x2.
__global__ __launch_bounds__(256, 2) void gemm_bt(
    const ushort* __restrict__ A, const ushort* __restrict__ Bt,
    void* __restrict__ C, int K, int lda, int ldb, int ldc,
    long aZ, long bZ, long cZ, int c_f32) {
    __shared__ __align__(16) ushort As[64][72];
    __shared__ __align__(16) ushort Bs[64][72];
    const int z = blockIdx.z;
    const ushort* Ab = A + (long)z * aZ;
    const ushort* Bb = Bt + (long)z * bZ;
    const long m0 = (long)blockIdx.y * 64;
    const long n0 = (long)blockIdx.x * 64;
    const int tid = threadIdx.x;
    const int lane = tid & 63, w = tid >> 6;
    const int wm = (w >> 1) * 32, wn = (w & 1) * 32;
    const int lrow = lane & 15, quad = lane >> 4;

    floatx4 acc[2][2] = {};

    const int r0_ = tid >> 3, c0_ = (tid & 7) * 8;          // slot tid
    const int r1_ = r0_ + 32, c1_ = c0_;                    // slot tid+256

    for (int k0 = 0; k0 < K; k0 += 64) {
        uint4 a0 = *(const uint4*)(Ab + (m0 + r0_) * lda + k0 + c0_);
        uint4 a1 = *(const uint4*)(Ab + (m0 + r1_) * lda + k0 + c1_);
        uint4 b0 = *(const uint4*)(Bb + (n0 + r0_) * ldb + k0 + c0_);
        uint4 b1 = *(const uint4*)(Bb + (n0 + r1_) * ldb + k0 + c1_);
        __syncthreads();
        *(uint4*)&As[r0_][c0_] = a0;
        *(uint4*)&As[r1_][c1_] = a1;
        *(uint4*)&Bs[r0_][c0_] = b0;
        *(uint4*)&Bs[r1_][c1_] = b1;
        __syncthreads();
        #pragma unroll
        for (int kk = 0; kk < 64; kk += 32) {
            bf16x8 af0 = ldb8(&As[wm + lrow][kk + quad * 8]);
            bf16x8 af1 = ldb8(&As[wm + 16 + lrow][kk + quad * 8]);
            bf16x8 bf0 = ldb8(&Bs[wn + lrow][kk + quad * 8]);
            bf16x8 bf1 = ldb8(&Bs[wn + 16 + lrow][kk + quad * 8]);
            acc[0][0] = MFMA(af0, bf0, acc[0][0]);
            acc[0][1] = MFMA(af0, bf1, acc[0][1]);
            acc[1][0] = MFMA(af1, bf0, acc[1][0]);
            acc[1][1] = MFMA(af1, bf1, acc[1][1]);
        }
    }
    if (c_f32) {
        float* Cb = (float*)C + (long)z * cZ;
        #pragma unroll
        for (int mt = 0; mt < 2; ++mt)
            #pragma unroll
            for (int nt = 0; nt < 2; ++nt)
                #pragma unroll
                for (int r = 0; r < 4; ++r) {
                    long row = m0 + wm + mt * 16 + quad * 4 + r;
                    long col = n0 + wn + nt * 16 + lrow;
                    Cb[row * ldc + col] = acc[mt][nt][r];
                }
    } else {
        ushort* Cb = (ushort*)C + (long)z * cZ;
        #pragma unroll
        for (int mt = 0; mt < 2; ++mt)
            #pragma unroll
            for (int nt = 0; nt < 2; ++nt)
                #pragma unroll
                for (int r = 0; r < 4; ++r) {
                    long row = m0 + wm + mt * 16 + quad * 4 + r;
                    long col = n0 + wn + nt * 16 + lrow;
                    Cb[row * ldc + col] = f2bf(acc[mt][nt][r]);
                }
    }
}

// ---------------------------------------------------------------- RMSNorm D=1536 (supports in==out; w is fp32)
__global__ __launch_bounds__(256) void rms1536(
    const ushort* in, const float* __restrict__ w, ushort* out) {
    const int row = blockIdx.x, t = threadIdx.x;
    const ushort* ip = in + (long)row * 1536;
    float v[6]; float ss = 0.f;
    #pragma unroll
    for (int i = 0; i < 6; ++i) { v[i] = bf2f(ip[i * 256 + t]); ss += v[i] * v[i]; }
    __shared__ float red[256];
    red[t] = ss; __syncthreads();
    for (int st = 128; st > 0; st >>= 1) { if (t < st) red[t] += red[t + st]; __syncthreads(); }
    const float sc = rsqrtf(red[0] * (1.f / 1536.f) + 1e-6f);
    ushort* op = out + (long)row * 1536;
    #pragma unroll
    for (int i = 0; i < 6; ++i) op[i * 256 + t] = f2bf(v[i] * sc * w[i * 256 + t]);
}

// ---------------------------------------------------------------- q RoPE: q (4096,3072) -> q_pe (4096,16,64); freqs fp32
__global__ __launch_bounds__(256) void qrope(
    const ushort* __restrict__ q, const float* __restrict__ freqs,
    ushort* __restrict__ qpe) {
    const int tok = blockIdx.x;
    const int s = tok & 2047;
    const int t = threadIdx.x;
    #pragma unroll
    for (int p = 0; p < 2; ++p) {
        const int idx = p * 256 + t;
        const int h = idx >> 5, i = idx & 31;
        const long base = (long)tok * 3072 + h * 192 + 128 + 2 * i;
        float x0 = bf2f(q[base]), x1 = bf2f(q[base + 1]);
        float th = freqs[s * 32 + i];
        float sn = sinf(th), cs = cosf(th);
        const long ob = (long)tok * 1024 + h * 64 + 2 * i;
        qpe[ob]     = f2bf(x0 * cs - x1 * sn);
        qpe[ob + 1] = f2bf(x0 * sn + x1 * cs);
    }
}

// ---------------------------------------------------------------- kv prep: rmsnorm(c_kv) -> kvc & kvcT, rope(k_pe)
__global__ __launch_bounds__(256) void kvprep(
    const ushort* __restrict__ kv, const float* __restrict__ w,
    const float* __restrict__ freqs, ushort* __restrict__ kvc,
    ushort* __restrict__ kvcT, ushort* __restrict__ kpe) {
    const int tok = blockIdx.x;
    const int b = tok >> 11, s = tok & 2047;
    const int t = threadIdx.x;
    const float v0 = bf2f(kv[(long)tok * 576 + t]);
    const float v1 = bf2f(kv[(long)tok * 576 + 256 + t]);
    __shared__ float red[256];
    red[t] = v0 * v0 + v1 * v1; __syncthreads();
    for (int st = 128; st > 0; st >>= 1) { if (t < st) red[t] += red[t + st]; __syncthreads(); }
    const float sc = rsqrtf(red[0] * (1.f / 512.f) + 1e-6f);
    const float y0 = v0 * sc * w[t];
    const float y1 = v1 * sc * w[256 + t];
    kvc[(long)tok * 512 + t] = f2bf(y0);
    kvc[(long)tok * 512 + 256 + t] = f2bf(y1);
    kvcT[(long)b * 1048576 + (long)t * 2048 + s] = f2bf(y0);
    kvcT[(long)b * 1048576 + (long)(256 + t) * 2048 + s] = f2bf(y1);
    if (t < 32) {
        float x0 = bf2f(kv[(long)tok * 576 + 512 + 2 * t]);
        float x1 = bf2f(kv[(long)tok * 576 + 512 + 2 * t + 1]);
        float th = freqs[s * 32 + t];
        float sn = sinf(th), cs = cosf(th);
        kpe[(long)tok * 64 + 2 * t]     = f2bf(x0 * cs - x1 * sn);
        kpe[(long)tok * 64 + 2 * t + 1] = f2bf(x0 * sn + x1 * cs);
    }
}

// ---------------------------------------------------------------- flash attention (O written IN PLACE over q_abs)
// grid (32 qtiles, 16 heads, 2 batch), 4 waves; wave w handles q rows [qt*64+w*16, +16)
// Safe: each block reads its entire q_abs slice into registers before the K-loop,
// and no other block touches that slice.
__global__ __launch_bounds__(256, 1) void mla_attn(
    ushort* __restrict__ qo,           // in: q_abs (4096,16,512); out: o (same)
    const ushort* __restrict__ q_pe,   // (4096,16,64)
    const ushort* __restrict__ kvc,    // (4096,512)
    const ushort* __restrict__ kvcT,   // (2,512,2048)
    const ushort* __restrict__ kpe) {  // (4096,64)
    const int qt = blockIdx.x, h = blockIdx.y, b = blockIdx.z;
    const int tid = threadIdx.x, lane = tid & 63, w = tid >> 6;
    const int lrow = lane & 15, quad = lane >> 4;
    const int qrow = qt * 64 + w * 16;
    const long tokb = (long)b * 2048 + qrow;

    __shared__ __align__(16) ushort P[4][16][72];

    bf16x8 qa[18];
    {
        const ushort* qp_ = qo + (tokb + lrow) * 8192 + h * 512 + quad * 8;
        #pragma unroll
        for (int ks = 0; ks < 16; ++ks) qa[ks] = ldb8(qp_ + ks * 32);
        const ushort* qq = q_pe + (tokb + lrow) * 1024 + h * 64 + quad * 8;
        qa[16] = ldb8(qq); qa[17] = ldb8(qq + 32);
    }

    floatx4 oacc[32] = {};
    float m_i[4] = {-1e30f, -1e30f, -1e30f, -1e30f};
    float l_i[4] = {0.f, 0.f, 0.f, 0.f};
    const float scale = 0.07216878364870323f;  // 192^-0.5

    for (int t = 0; t <= qt; ++t) {
        const int kv0 = t * 64;
        floatx4 sacc[4] = {};
        const ushort* kbase[4]; const ushort* pbase[4];
        #pragma unroll
        for (int nt = 0; nt < 4; ++nt) {
            long rr = (long)b * 2048 + kv0 + nt * 16 + lrow;
            kbase[nt] = kvc + rr * 512 + quad * 8;
            pbase[nt] = kpe + rr * 64 + quad * 8;
        }
        #pragma unroll
        for (int ks = 0; ks < 16; ++ks)
            #pragma unroll
            for (int nt = 0; nt < 4; ++nt)
                sacc[nt] = MFMA(qa[ks], ldb8(kbase[nt] + ks * 32), sacc[nt]);
        #pragma unroll
        for (int j = 0; j < 2; ++j)
            #pragma unroll
            for (int nt = 0; nt < 4; ++nt)
                sacc[nt] = MFMA(qa[16 + j], ldb8(pbase[nt] + j * 32), sacc[nt]);

        // online softmax (per row r, owned by this quad; reduce across the 16 lanes sharing the row)
        #pragma unroll
        for (int r = 0; r < 4; ++r) {
            const int row_s = qrow + quad * 4 + r;
            float pv[4]; float smax = -1e30f;
            #pragma unroll
            for (int nt = 0; nt < 4; ++nt) {
                float sv = sacc[nt][r] * scale;
                if (kv0 + nt * 16 + lrow > row_s) sv = -1e30f;  // causal
                pv[nt] = sv;
                smax = fmaxf(smax, sv);
            }
            #pragma unroll
            for (int off = 1; off < 16; off <<= 1)
                smax = fmaxf(smax, __shfl_xor(smax, off));
            const float mnew = fmaxf(m_i[r], smax);
            const float alpha = __expf(m_i[r] - mnew);
            float ps = 0.f;
            #pragma unroll
            for (int nt = 0; nt < 4; ++nt) {
                float p = __expf(pv[nt] - mnew);
                ps += p;
                P[w][quad * 4 + r][nt * 16 + lrow] = f2bf(p);
            }
            #pragma unroll
            for (int off = 1; off < 16; off <<= 1)
                ps += __shfl_xor(ps, off);
            l_i[r] = l_i[r] * alpha + ps;
            m_i[r] = mnew;
            #pragma unroll
            for (int v = 0; v < 32; ++v) oacc[v][r] *= alpha;
        }

        // PV: P (16x64, A-layout from LDS) x V^T rows (contiguous in kv dim)
        #pragma unroll
        for (int ks = 0; ks < 2; ++ks) {
            bf16x8 pf = ldb8(&P[w][lrow][ks * 32 + quad * 8]);
            const ushort* vb = kvcT + (long)b * 1048576 + (long)lrow * 2048 + kv0 + ks * 32 + quad * 8;
            #pragma unroll
            for (int v = 0; v < 32; ++v) {
                bf16x8 vf = ldb8(vb + (long)v * 16 * 2048);
                oacc[v] = MFMA(pf, vf, oacc[v]);
            }
        }
    }

    #pragma unroll
    for (int v = 0; v < 32; ++v)
        #pragma unroll
        for (int r = 0; r < 4; ++r) {
            long tok = tokb + quad * 4 + r;
            qo[tok * 8192 + h * 512 + v * 16 + lrow] = f2bf(oacc[v][r] / l_i[r]);
        }
}

// ---------------------------------------------------------------- launcher
extern "C" void kernel_launch(void* const* d_in, const int* in_sizes, int n_in,
                              void* d_out, int out_size, void* d_ws, size_t ws_size,
                              hipStream_t stream) {
    // ALL array inputs are fp32 per the reference (jnp.float32).
    const float* x      = (const float*)d_in[0];   // (2,2048,2048)
    const float* freqs  = (const float*)d_in[1];   // (2048,32)
    // d_in[2] = start_pos (int, ==0, unused)
    const float* wq_a   = (const float*)d_in[3];   // (2048,1536)
    const float* qnw    = (const float*)d_in[4];   // (1536,)
    const float* wq_b   = (const float*)d_in[5];   // (1536,3072)
    const float* wkv_a  = (const float*)d_in[6];   // (2048,576)
    const float* kvnw   = (const float*)d_in[7];   // (512,)
    const float* wkv_b  = (const float*)d_in[8];   // (512,4096)
    const float* wo     = (const float*)d_in[9];   // (2048,2048)
    float* out = (float*)d_out;                    // (2,2048,2048) fp32
    (void)ws_size; (void)in_sizes; (void)n_in; (void)out_size;

    // ---- compact overlay arena (peak ~120.5 MiB) ----
    char* ws = (char*)d_ws;
    // Slab A (0 .. 64 MiB): q_abs final occupant; early occupants all die before the q_abs GEMM.
    ushort* q_abs  = (ushort*)(ws + 0);            // 33,554,432 elem (64 MiB)
    ushort* q_lat  = (ushort*)(ws + 0);            //  6,291,456 elem
    ushort* kv     = (ushort*)(ws + 12582912);     //  2,359,296 elem
    ushort* xb     = (ushort*)(ws + 17301504);     //  8,388,608 elem (dies after kv GEMM)
    ushort* wq_aT  = (ushort*)(ws + 34078720);     //  3,145,728 elem
    ushort* wq_bT  = (ushort*)(ws + 40370176);     //  4,718,592 elem
    ushort* wkv_aT = (ushort*)(ws + 49807360);     //  1,179,648 elem (ends 52,166,656 < 67,108,864)
    // Slab B: q dies after the q_abs GEMM; o2 reuses it.
    ushort* q      = (ushort*)(ws + 67108864);     // 12,582,912 elem
    ushort* o2     = (ushort*)(ws + 67108864);     //  8,388,608 elem
    // Persistent tail.
    ushort* qpe    = (ushort*)(ws + 92274688);     //  4,194,304 elem
    ushort* kvc    = (ushort*)(ws + 100663296);    //  2,097,152 elem
    ushort* kvcT   = (ushort*)(ws + 104857600);    //  2,097,152 elem
    ushort* kpe    = (ushort*)(ws + 109051904);    //    262,144 elem
    ushort* wkv_bC = (ushort*)(ws + 109576192);    //  2,097,152 elem (wkv_b cast, same layout)
    ushort* wkv_bT = (ushort*)(ws + 113770496);    //  2,097,152 elem
    ushort* woT    = (ushort*)(ws + 117964800);    //  4,194,304 elem (ends 126,353,408 B)

    dim3 tb(32, 8);
    // weight ingestion: cast(+transpose) fp32 -> bf16
    transpose_f32_bf16<<<dim3(48, 64), tb, 0, stream>>>(wq_a, wq_aT, 2048, 1536);
    transpose_f32_bf16<<<dim3(96, 48), tb, 0, stream>>>(wq_b, wq_bT, 1536, 3072);
    transpose_f32_bf16<<<dim3(18, 64), tb, 0, stream>>>(wkv_a, wkv_aT, 2048, 576);
    transpose_f32_bf16<<<dim3(128, 16), tb, 0, stream>>>(wkv_b, wkv_bT, 512, 4096);
    transpose_f32_bf16<<<dim3(64, 64), tb, 0, stream>>>(wo, woT, 2048, 2048);
    cvt_f32_bf16<<<8192, 256, 0, stream>>>(x, xb, 8388608L);
    cvt_f32_bf16<<<2048, 256, 0, stream>>>(wkv_b, wkv_bC, 2097152L);

    // q_lat = x @ wq_a            (4096 x 1536, K=2048)
    gemm_bt<<<dim3(24, 64, 1), 256, 0, stream>>>(xb, wq_aT, q_lat, 2048, 2048, 2048, 1536, 0, 0, 0, 0);
    // qn = rmsnorm(q_lat) * q_norm_w   (in place)
    rms1536<<<4096, 256, 0, stream>>>(q_lat, qnw, q_lat);
    // q = qn @ wq_b               (4096 x 3072, K=1536)
    gemm_bt<<<dim3(48, 64, 1), 256, 0, stream>>>(q_lat, wq_bT, q, 1536, 1536, 1536, 3072, 0, 0, 0, 0);
    // q_pe = rope(q[..., 128:192])
    qrope<<<4096, 256, 0, stream>>>(q, freqs, qpe);
    // kv = x @ wkv_a              (4096 x 576, K=2048)
    gemm_bt<<<dim3(9, 64, 1), 256, 0, stream>>>(xb, wkv_aT, kv, 2048, 2048, 2048, 576, 0, 0, 0, 0);
    // kvc / kvcT = rmsnorm(kv[:,:512]); kpe = rope(kv[:,512:])
    kvprep<<<4096, 256, 0, stream>>>(kv, kvnw, freqs, kvc, kvcT, kpe);
    // q_abs[h] = q_nope[h] @ wkv_b_mat[h,:128]^T  (Bt rows = wkv_bC rows, stride 4096, head offset 256)
    // NOTE: overwrites all of slab A — q_lat/kv/xb/wq_aT/wq_bT/wkv_aT are dead by here.
    gemm_bt<<<dim3(8, 64, 16), 256, 0, stream>>>(q, wkv_bC, q_abs, 128, 3072, 4096, 8192, 192, 256, 512, 0);
    // flash attention; O overwrites q_abs in place
    mla_attn<<<dim3(32, 16, 2), 256, 0, stream>>>(q_abs, qpe, kvc, kvcT, kpe);
    // o2[h] = o[h] @ wkv_b_mat[h,128:]   (Bt rows = wkv_bT rows 128..255 per head); o2 reuses q's region
    gemm_bt<<<dim3(2, 64, 16), 256, 0, stream>>>(q_abs, wkv_bT + 128L * 512, o2, 512, 8192, 512, 2048, 512, 131072, 128, 0);
    // out = o2 @ wo   (fp32 output)
    gemm_bt<<<dim3(32, 64, 1), 256, 0, stream>>>(o2, woT, out, 2048, 2048, 2048, 2048, 0, 0, 0, 1);
}

// Round 4
// 1038.602 us; speedup vs baseline: 2.9515x; 2.9515x over previous
//
#include <hip/hip_runtime.h>

typedef __bf16 bf16x8 __attribute__((ext_vector_type(8)));
typedef float floatx4 __attribute__((ext_vector_type(4)));

#define MFMA(a, b, c) __builtin_amdgcn_mfma_f32_16x16x32_bf16((a), (b), (c), 0, 0, 0)

__device__ __forceinline__ float bf2f(ushort u) {
    union { unsigned int i; float f; } v; v.i = ((unsigned int)u) << 16; return v.f;
}
__device__ __forceinline__ ushort f2bf(float f) {
    union { float f; unsigned int i; } v; v.f = f;
    unsigned int r = v.i + 0x7fffu + ((v.i >> 16) & 1u);
    return (ushort)(r >> 16);
}
__device__ __forceinline__ bf16x8 ldb8(const ushort* p) { return *(const bf16x8*)p; }

// ---------------------------------------------------------------- fp32 -> bf16 transpose
__global__ __launch_bounds__(256) void transpose_f32_bf16(
    const float* __restrict__ in, ushort* __restrict__ out, int R, int C) {
    __shared__ ushort tile[32][33];
    const int c0 = blockIdx.x * 32, r0 = blockIdx.y * 32;
    const int tx = threadIdx.x, ty = threadIdx.y;
    #pragma unroll
    for (int i = 0; i < 32; i += 8) {
        int r = r0 + ty + i, c = c0 + tx;
        if (r < R && c < C) tile[ty + i][tx] = f2bf(in[(long)r * C + c]);
    }
    __syncthreads();
    #pragma unroll
    for (int i = 0; i < 32; i += 8) {
        int r = c0 + ty + i, c = r0 + tx;   // out is C x R
        if (r < C && c < R) out[(long)r * R + c] = tile[tx][ty + i];
    }
}

// ---------------------------------------------------------------- fp32 -> bf16 elementwise (n % 4 == 0)
__global__ __launch_bounds__(256) void cvt_f32_bf16(
    const float* __restrict__ in, ushort* __restrict__ out, long n) {
    const long i = ((long)blockIdx.x * 256 + threadIdx.x) * 4;
    if (i >= n) return;
    float4 v = *(const float4*)(in + i);
    ushort4 o;
    o.x = f2bf(v.x); o.y = f2bf(v.y); o.z = f2bf(v.z); o.w = f2bf(v.w);
    *(ushort4*)(out + i) = o;
}

// ---------------------------------------------------------------- GEMM C = A * B^T (bf16 in; bf16 or fp32 out)
__global__ __launch_bounds__(256, 2) void gemm_bt(
    const ushort* __restrict__ A, const ushort* __restrict__ Bt,
    void* __restrict__ C, int K, int lda, int ldb, int ldc,
    long aZ, long bZ, long cZ, int c_f32) {
    __shared__ __align__(16) ushort As[64][72];
    __shared__ __align__(16) ushort Bs[64][72];
    const int z = blockIdx.z;
    const ushort* Ab = A + (long)z * aZ;
    const ushort* Bb = Bt + (long)z * bZ;
    const long m0 = (long)blockIdx.y * 64;
    const long n0 = (long)blockIdx.x * 64;
    const int tid = threadIdx.x;
    const int lane = tid & 63, w = tid >> 6;
    const int wm = (w >> 1) * 32, wn = (w & 1) * 32;
    const int lrow = lane & 15, quad = lane >> 4;

    floatx4 acc[2][2] = {};

    const int r0_ = tid >> 3, c0_ = (tid & 7) * 8;
    const int r1_ = r0_ + 32, c1_ = c0_;

    for (int k0 = 0; k0 < K; k0 += 64) {
        uint4 a0 = *(const uint4*)(Ab + (m0 + r0_) * lda + k0 + c0_);
        uint4 a1 = *(const uint4*)(Ab + (m0 + r1_) * lda + k0 + c1_);
        uint4 b0 = *(const uint4*)(Bb + (n0 + r0_) * ldb + k0 + c0_);
        uint4 b1 = *(const uint4*)(Bb + (n0 + r1_) * ldb + k0 + c1_);
        __syncthreads();
        *(uint4*)&As[r0_][c0_] = a0;
        *(uint4*)&As[r1_][c1_] = a1;
        *(uint4*)&Bs[r0_][c0_] = b0;
        *(uint4*)&Bs[r1_][c1_] = b1;
        __syncthreads();
        #pragma unroll
        for (int kk = 0; kk < 64; kk += 32) {
            bf16x8 af0 = ldb8(&As[wm + lrow][kk + quad * 8]);
            bf16x8 af1 = ldb8(&As[wm + 16 + lrow][kk + quad * 8]);
            bf16x8 bf0 = ldb8(&Bs[wn + lrow][kk + quad * 8]);
            bf16x8 bf1 = ldb8(&Bs[wn + 16 + lrow][kk + quad * 8]);
            acc[0][0] = MFMA(af0, bf0, acc[0][0]);
            acc[0][1] = MFMA(af0, bf1, acc[0][1]);
            acc[1][0] = MFMA(af1, bf0, acc[1][0]);
            acc[1][1] = MFMA(af1, bf1, acc[1][1]);
        }
    }
    if (c_f32) {
        float* Cb = (float*)C + (long)z * cZ;
        #pragma unroll
        for (int mt = 0; mt < 2; ++mt)
            #pragma unroll
            for (int nt = 0; nt < 2; ++nt)
                #pragma unroll
                for (int r = 0; r < 4; ++r) {
                    long row = m0 + wm + mt * 16 + quad * 4 + r;
                    long col = n0 + wn + nt * 16 + lrow;
                    Cb[row * ldc + col] = acc[mt][nt][r];
                }
    } else {
        ushort* Cb = (ushort*)C + (long)z * cZ;
        #pragma unroll
        for (int mt = 0; mt < 2; ++mt)
            #pragma unroll
            for (int nt = 0; nt < 2; ++nt)
                #pragma unroll
                for (int r = 0; r < 4; ++r) {
                    long row = m0 + wm + mt * 16 + quad * 4 + r;
                    long col = n0 + wn + nt * 16 + lrow;
                    Cb[row * ldc + col] = f2bf(acc[mt][nt][r]);
                }
    }
}

// ---------------------------------------------------------------- RMSNorm D=1536 (supports in==out; w is fp32)
__global__ __launch_bounds__(256) void rms1536(
    const ushort* in, const float* __restrict__ w, ushort* out) {
    const int row = blockIdx.x, t = threadIdx.x;
    const ushort* ip = in + (long)row * 1536;
    float v[6]; float ss = 0.f;
    #pragma unroll
    for (int i = 0; i < 6; ++i) { v[i] = bf2f(ip[i * 256 + t]); ss += v[i] * v[i]; }
    __shared__ float red[256];
    red[t] = ss; __syncthreads();
    for (int st = 128; st > 0; st >>= 1) { if (t < st) red[t] += red[t + st]; __syncthreads(); }
    const float sc = rsqrtf(red[0] * (1.f / 1536.f) + 1e-6f);
    ushort* op = out + (long)row * 1536;
    #pragma unroll
    for (int i = 0; i < 6; ++i) op[i * 256 + t] = f2bf(v[i] * sc * w[i * 256 + t]);
}

// ---------------------------------------------------------------- q RoPE
__global__ __launch_bounds__(256) void qrope(
    const ushort* __restrict__ q, const float* __restrict__ freqs,
    ushort* __restrict__ qpe) {
    const int tok = blockIdx.x;
    const int s = tok & 2047;
    const int t = threadIdx.x;
    #pragma unroll
    for (int p = 0; p < 2; ++p) {
        const int idx = p * 256 + t;
        const int h = idx >> 5, i = idx & 31;
        const long base = (long)tok * 3072 + h * 192 + 128 + 2 * i;
        float x0 = bf2f(q[base]), x1 = bf2f(q[base + 1]);
        float th = freqs[s * 32 + i];
        float sn = sinf(th), cs = cosf(th);
        const long ob = (long)tok * 1024 + h * 64 + 2 * i;
        qpe[ob]     = f2bf(x0 * cs - x1 * sn);
        qpe[ob + 1] = f2bf(x0 * sn + x1 * cs);
    }
}

// ---------------------------------------------------------------- kv prep
__global__ __launch_bounds__(256) void kvprep(
    const ushort* __restrict__ kv, const float* __restrict__ w,
    const float* __restrict__ freqs, ushort* __restrict__ kvc,
    ushort* __restrict__ kvcT, ushort* __restrict__ kpe) {
    const int tok = blockIdx.x;
    const int b = tok >> 11, s = tok & 2047;
    const int t = threadIdx.x;
    const float v0 = bf2f(kv[(long)tok * 576 + t]);
    const float v1 = bf2f(kv[(long)tok * 576 + 256 + t]);
    __shared__ float red[256];
    red[t] = v0 * v0 + v1 * v1; __syncthreads();
    for (int st = 128; st > 0; st >>= 1) { if (t < st) red[t] += red[t + st]; __syncthreads(); }
    const float sc = rsqrtf(red[0] * (1.f / 512.f) + 1e-6f);
    const float y0 = v0 * sc * w[t];
    const float y1 = v1 * sc * w[256 + t];
    kvc[(long)tok * 512 + t] = f2bf(y0);
    kvc[(long)tok * 512 + 256 + t] = f2bf(y1);
    kvcT[(long)b * 1048576 + (long)t * 2048 + s] = f2bf(y0);
    kvcT[(long)b * 1048576 + (long)(256 + t) * 2048 + s] = f2bf(y1);
    if (t < 32) {
        float x0 = bf2f(kv[(long)tok * 576 + 512 + 2 * t]);
        float x1 = bf2f(kv[(long)tok * 576 + 512 + 2 * t + 1]);
        float th = freqs[s * 32 + t];
        float sn = sinf(th), cs = cosf(th);
        kpe[(long)tok * 64 + 2 * t]     = f2bf(x0 * cs - x1 * sn);
        kpe[(long)tok * 64 + 2 * t + 1] = f2bf(x0 * sn + x1 * cs);
    }
}

// ---------------------------------------------------------------- flash attention v2
// Grid (16, 16, 2): block handles q-tiles {qx, 31-qx} (constant 66 kv-iters -> perfect balance),
// 4 waves, K-tile (32 kv x 512) staged in LDS (pad 520), kpe direct-global.
// QK^T: wave w owns q-rows [w*16,+16) (verified 16x16x32 layouts). Softmax in-reg, P -> LDS.
// PV role-remap: wave w owns v-slice [w*128,+128) x all 64 q-rows; V b-frags from L2 kvcT.
// O written in place over q_abs (block-exclusive slice; Q consumed into regs at tile start).
__global__ __launch_bounds__(256, 2) void mla_attn2(
    ushort* __restrict__ qo,           // in: q_abs (4096,16,512); out: O (same)
    const ushort* __restrict__ q_pe,   // (4096,16,64)
    const ushort* __restrict__ kvc,    // (4096,512)
    const ushort* __restrict__ kvcT,   // (2,512,2048)
    const ushort* __restrict__ kpe) {  // (4096,64)
    __shared__ __align__(16) ushort Ks[32][520];
    __shared__ __align__(16) ushort P[64][72];  // cols 64-65: alpha(f32), 66-67: l(f32)
    const int qx = blockIdx.x, h = blockIdx.y, b = blockIdx.z;
    const int tid = threadIdx.x, lane = tid & 63, w = tid >> 6;
    const int lrow = lane & 15, quad = lane >> 4;
    const long bb = (long)b * 2048;
    const float scale = 0.07216878364870323f;  // 192^-0.5
    const int srow = tid >> 3, scseg = (tid & 7) * 64;  // staging map

    for (int half = 0; half < 2; ++half) {
        const int qt = half ? (31 - qx) : qx;
        const int qrow = qt * 64;
        const long tokb = bb + qrow;

        // Q fragments (wave w: rows w*16 .. +16)
        bf16x8 qa[18];
        {
            const ushort* qp_ = qo + (tokb + w * 16 + lrow) * 8192 + h * 512 + quad * 8;
            #pragma unroll
            for (int ks = 0; ks < 16; ++ks) qa[ks] = ldb8(qp_ + ks * 32);
            const ushort* qq = q_pe + (tokb + w * 16 + lrow) * 1024 + h * 64 + quad * 8;
            qa[16] = ldb8(qq); qa[17] = ldb8(qq + 32);
        }

        floatx4 oacc[4][8] = {};        // [m-frag][v-frag]
        float m_i[4], l_i[4];
        #pragma unroll
        for (int r = 0; r < 4; ++r) { m_i[r] = -1e30f; l_i[r] = 0.f; }

        const int niter = (qt + 1) * 2;
        for (int t = 0; t < niter; ++t) {
            const int kv0 = t * 32;
            // ---- stage K-tile (32 x 512) into LDS ----
            {
                const ushort* src = kvc + (bb + kv0 + srow) * 512 + scseg;
                #pragma unroll
                for (int j = 0; j < 8; ++j) {
                    uint4 v = *(const uint4*)(src + j * 8);
                    *(uint4*)&Ks[srow][scseg + j * 8] = v;
                }
            }
            __syncthreads();  // A: stage visible; prev-iter PV done (P safe to rewrite)

            // ---- QK^T (rows w*16..+16 x kv-cols 0..31) ----
            floatx4 sacc[2] = {};
            const ushort* pb0 = kpe + (bb + kv0 + lrow) * 64 + quad * 8;
            const ushort* pb1 = kpe + (bb + kv0 + 16 + lrow) * 64 + quad * 8;
            bf16x8 kp00 = ldb8(pb0), kp01 = ldb8(pb0 + 32);
            bf16x8 kp10 = ldb8(pb1), kp11 = ldb8(pb1 + 32);
            #pragma unroll
            for (int ks = 0; ks < 16; ++ks) {
                bf16x8 b0 = ldb8(&Ks[lrow][ks * 32 + quad * 8]);
                bf16x8 b1 = ldb8(&Ks[16 + lrow][ks * 32 + quad * 8]);
                sacc[0] = MFMA(qa[ks], b0, sacc[0]);
                sacc[1] = MFMA(qa[ks], b1, sacc[1]);
            }
            sacc[0] = MFMA(qa[16], kp00, sacc[0]);
            sacc[0] = MFMA(qa[17], kp01, sacc[0]);
            sacc[1] = MFMA(qa[16], kp10, sacc[1]);
            sacc[1] = MFMA(qa[17], kp11, sacc[1]);

            // ---- prefetch V b-frags (independent of P) to overlap barrier ----
            bf16x8 vf[8];
            {
                const ushort* vb = kvcT + (long)b * 1048576 + (long)(w * 128 + lrow) * 2048 + kv0 + quad * 8;
                #pragma unroll
                for (int nf = 0; nf < 8; ++nf) vf[nf] = ldb8(vb + (long)nf * 16 * 2048);
            }

            // ---- online softmax (rows w*16 + quad*4 + r) ----
            #pragma unroll
            for (int r = 0; r < 4; ++r) {
                const int rloc = w * 16 + quad * 4 + r;
                const int row_s = qrow + rloc;
                float pv0 = sacc[0][r] * scale;
                float pv1 = sacc[1][r] * scale;
                if (kv0 + lrow > row_s)      pv0 = -1e30f;
                if (kv0 + 16 + lrow > row_s) pv1 = -1e30f;
                float smax = fmaxf(pv0, pv1);
                #pragma unroll
                for (int off = 1; off < 16; off <<= 1)
                    smax = fmaxf(smax, __shfl_xor(smax, off));
                const float mnew = fmaxf(m_i[r], smax);
                const float alpha = __expf(m_i[r] - mnew);
                float p0 = __expf(pv0 - mnew);
                float p1 = __expf(pv1 - mnew);
                P[rloc][lrow]      = f2bf(p0);
                P[rloc][16 + lrow] = f2bf(p1);
                float ps = p0 + p1;
                #pragma unroll
                for (int off = 1; off < 16; off <<= 1)
                    ps += __shfl_xor(ps, off);
                l_i[r] = l_i[r] * alpha + ps;
                m_i[r] = mnew;
                if (lrow == 0) *(float*)&P[rloc][64] = alpha;
            }
            __syncthreads();  // B: P + alpha visible

            // ---- PV: wave w owns v-slice [w*128,+128), all 64 q-rows ----
            #pragma unroll
            for (int mf = 0; mf < 4; ++mf) {
                float al[4];
                #pragma unroll
                for (int r = 0; r < 4; ++r) al[r] = *(const float*)&P[mf * 16 + quad * 4 + r][64];
                #pragma unroll
                for (int nf = 0; nf < 8; ++nf)
                    #pragma unroll
                    for (int r = 0; r < 4; ++r) oacc[mf][nf][r] *= al[r];
                bf16x8 pf = ldb8(&P[mf * 16 + lrow][quad * 8]);
                #pragma unroll
                for (int nf = 0; nf < 8; ++nf)
                    oacc[mf][nf] = MFMA(pf, vf[nf], oacc[mf][nf]);
            }
        }

        // ---- epilogue: publish l, divide, store O in place ----
        {
            #pragma unroll
            for (int r = 0; r < 4; ++r)
                if (lrow == 0) *(float*)&P[w * 16 + quad * 4 + r][66] = l_i[r];
        }
        __syncthreads();
        #pragma unroll
        for (int mf = 0; mf < 4; ++mf) {
            float li[4];
            #pragma unroll
            for (int r = 0; r < 4; ++r) li[r] = *(const float*)&P[mf * 16 + quad * 4 + r][66];
            #pragma unroll
            for (int nf = 0; nf < 8; ++nf)
                #pragma unroll
                for (int r = 0; r < 4; ++r) {
                    long tok = tokb + mf * 16 + quad * 4 + r;
                    qo[tok * 8192 + h * 512 + w * 128 + nf * 16 + lrow] = f2bf(oacc[mf][nf][r] / li[r]);
                }
        }
        __syncthreads();  // protect P/Ks before next half
    }
}

// ---------------------------------------------------------------- launcher
extern "C" void kernel_launch(void* const* d_in, const int* in_sizes, int n_in,
                              void* d_out, int out_size, void* d_ws, size_t ws_size,
                              hipStream_t stream) {
    const float* x      = (const float*)d_in[0];
    const float* freqs  = (const float*)d_in[1];
    const float* wq_a   = (const float*)d_in[3];
    const float* qnw    = (const float*)d_in[4];
    const float* wq_b   = (const float*)d_in[5];
    const float* wkv_a  = (const float*)d_in[6];
    const float* kvnw   = (const float*)d_in[7];
    const float* wkv_b  = (const float*)d_in[8];
    const float* wo     = (const float*)d_in[9];
    float* out = (float*)d_out;
    (void)ws_size; (void)in_sizes; (void)n_in; (void)out_size;

    char* ws = (char*)d_ws;
    ushort* q_abs  = (ushort*)(ws + 0);
    ushort* q_lat  = (ushort*)(ws + 0);
    ushort* kv     = (ushort*)(ws + 12582912);
    ushort* xb     = (ushort*)(ws + 17301504);
    ushort* wq_aT  = (ushort*)(ws + 34078720);
    ushort* wq_bT  = (ushort*)(ws + 40370176);
    ushort* wkv_aT = (ushort*)(ws + 49807360);
    ushort* q      = (ushort*)(ws + 67108864);
    ushort* o2     = (ushort*)(ws + 67108864);
    ushort* qpe    = (ushort*)(ws + 92274688);
    ushort* kvc    = (ushort*)(ws + 100663296);
    ushort* kvcT   = (ushort*)(ws + 104857600);
    ushort* kpe    = (ushort*)(ws + 109051904);
    ushort* wkv_bC = (ushort*)(ws + 109576192);
    ushort* wkv_bT = (ushort*)(ws + 113770496);
    ushort* woT    = (ushort*)(ws + 117964800);

    dim3 tb(32, 8);
    transpose_f32_bf16<<<dim3(48, 64), tb, 0, stream>>>(wq_a, wq_aT, 2048, 1536);
    transpose_f32_bf16<<<dim3(96, 48), tb, 0, stream>>>(wq_b, wq_bT, 1536, 3072);
    transpose_f32_bf16<<<dim3(18, 64), tb, 0, stream>>>(wkv_a, wkv_aT, 2048, 576);
    transpose_f32_bf16<<<dim3(128, 16), tb, 0, stream>>>(wkv_b, wkv_bT, 512, 4096);
    transpose_f32_bf16<<<dim3(64, 64), tb, 0, stream>>>(wo, woT, 2048, 2048);
    cvt_f32_bf16<<<8192, 256, 0, stream>>>(x, xb, 8388608L);
    cvt_f32_bf16<<<2048, 256, 0, stream>>>(wkv_b, wkv_bC, 2097152L);

    gemm_bt<<<dim3(24, 64, 1), 256, 0, stream>>>(xb, wq_aT, q_lat, 2048, 2048, 2048, 1536, 0, 0, 0, 0);
    rms1536<<<4096, 256, 0, stream>>>(q_lat, qnw, q_lat);
    gemm_bt<<<dim3(48, 64, 1), 256, 0, stream>>>(q_lat, wq_bT, q, 1536, 1536, 1536, 3072, 0, 0, 0, 0);
    qrope<<<4096, 256, 0, stream>>>(q, freqs, qpe);
    gemm_bt<<<dim3(9, 64, 1), 256, 0, stream>>>(xb, wkv_aT, kv, 2048, 2048, 2048, 576, 0, 0, 0, 0);
    kvprep<<<4096, 256, 0, stream>>>(kv, kvnw, freqs, kvc, kvcT, kpe);
    gemm_bt<<<dim3(8, 64, 16), 256, 0, stream>>>(q, wkv_bC, q_abs, 128, 3072, 4096, 8192, 192, 256, 512, 0);
    mla_attn2<<<dim3(16, 16, 2), 256, 0, stream>>>(q_abs, qpe, kvc, kvcT, kpe);
    gemm_bt<<<dim3(2, 64, 16), 256, 0, stream>>>(q_abs, wkv_bT + 128L * 512, o2, 512, 8192, 512, 2048, 512, 131072, 128, 0);
    gemm_bt<<<dim3(32, 64, 1), 256, 0, stream>>>(o2, woT, out, 2048, 2048, 2048, 2048, 0, 0, 0, 1);
}

// Round 6
// 870.788 us; speedup vs baseline: 3.5204x; 1.1927x over previous
//
#include <hip/hip_runtime.h>

typedef __bf16 bf16x8 __attribute__((ext_vector_type(8)));
typedef float floatx4 __attribute__((ext_vector_type(4)));

#define MFMA(a, b, c) __builtin_amdgcn_mfma_f32_16x16x32_bf16((a), (b), (c), 0, 0, 0)

__device__ __forceinline__ float bf2f(ushort u) {
    union { unsigned int i; float f; } v; v.i = ((unsigned int)u) << 16; return v.f;
}
__device__ __forceinline__ ushort f2bf(float f) {
    union { float f; unsigned int i; } v; v.f = f;
    unsigned int r = v.i + 0x7fffu + ((v.i >> 16) & 1u);
    return (ushort)(r >> 16);
}
__device__ __forceinline__ bf16x8 ldb8(const ushort* p) { return *(const bf16x8*)p; }

// ---------------------------------------------------------------- fp32 -> bf16 transpose
__global__ __launch_bounds__(256) void transpose_f32_bf16(
    const float* __restrict__ in, ushort* __restrict__ out, int R, int C) {
    __shared__ ushort tile[32][33];
    const int c0 = blockIdx.x * 32, r0 = blockIdx.y * 32;
    const int tx = threadIdx.x, ty = threadIdx.y;
    #pragma unroll
    for (int i = 0; i < 32; i += 8) {
        int r = r0 + ty + i, c = c0 + tx;
        if (r < R && c < C) tile[ty + i][tx] = f2bf(in[(long)r * C + c]);
    }
    __syncthreads();
    #pragma unroll
    for (int i = 0; i < 32; i += 8) {
        int r = c0 + ty + i, c = r0 + tx;   // out is C x R
        if (r < C && c < R) out[(long)r * R + c] = tile[tx][ty + i];
    }
}

// ---------------------------------------------------------------- fp32 -> bf16 elementwise (n % 4 == 0)
__global__ __launch_bounds__(256) void cvt_f32_bf16(
    const float* __restrict__ in, ushort* __restrict__ out, long n) {
    const long i = ((long)blockIdx.x * 256 + threadIdx.x) * 4;
    if (i >= n) return;
    float4 v = *(const float4*)(in + i);
    ushort4 o;
    o.x = f2bf(v.x); o.y = f2bf(v.y); o.z = f2bf(v.z); o.w = f2bf(v.w);
    *(ushort4*)(out + i) = o;
}

// ---------------------------------------------------------------- GEMM 64-tile (for N=576 case)
__global__ __launch_bounds__(256, 2) void gemm_bt(
    const ushort* __restrict__ A, const ushort* __restrict__ Bt,
    void* __restrict__ C, int K, int lda, int ldb, int ldc,
    long aZ, long bZ, long cZ, int c_f32) {
    __shared__ __align__(16) ushort As[64][72];
    __shared__ __align__(16) ushort Bs[64][72];
    const int z = blockIdx.z;
    const ushort* Ab = A + (long)z * aZ;
    const ushort* Bb = Bt + (long)z * bZ;
    const long m0 = (long)blockIdx.y * 64;
    const long n0 = (long)blockIdx.x * 64;
    const int tid = threadIdx.x;
    const int lane = tid & 63, w = tid >> 6;
    const int wm = (w >> 1) * 32, wn = (w & 1) * 32;
    const int lrow = lane & 15, quad = lane >> 4;

    floatx4 acc[2][2] = {};

    const int r0_ = tid >> 3, c0_ = (tid & 7) * 8;
    const int r1_ = r0_ + 32, c1_ = c0_;

    for (int k0 = 0; k0 < K; k0 += 64) {
        uint4 a0 = *(const uint4*)(Ab + (m0 + r0_) * lda + k0 + c0_);
        uint4 a1 = *(const uint4*)(Ab + (m0 + r1_) * lda + k0 + c1_);
        uint4 b0 = *(const uint4*)(Bb + (n0 + r0_) * ldb + k0 + c0_);
        uint4 b1 = *(const uint4*)(Bb + (n0 + r1_) * ldb + k0 + c1_);
        __syncthreads();
        *(uint4*)&As[r0_][c0_] = a0;
        *(uint4*)&As[r1_][c1_] = a1;
        *(uint4*)&Bs[r0_][c0_] = b0;
        *(uint4*)&Bs[r1_][c1_] = b1;
        __syncthreads();
        #pragma unroll
        for (int kk = 0; kk < 64; kk += 32) {
            bf16x8 af0 = ldb8(&As[wm + lrow][kk + quad * 8]);
            bf16x8 af1 = ldb8(&As[wm + 16 + lrow][kk + quad * 8]);
            bf16x8 bf0 = ldb8(&Bs[wn + lrow][kk + quad * 8]);
            bf16x8 bf1 = ldb8(&Bs[wn + 16 + lrow][kk + quad * 8]);
            acc[0][0] = MFMA(af0, bf0, acc[0][0]);
            acc[0][1] = MFMA(af0, bf1, acc[0][1]);
            acc[1][0] = MFMA(af1, bf0, acc[1][0]);
            acc[1][1] = MFMA(af1, bf1, acc[1][1]);
        }
    }
    if (c_f32) {
        float* Cb = (float*)C + (long)z * cZ;
        #pragma unroll
        for (int mt = 0; mt < 2; ++mt)
            #pragma unroll
            for (int nt = 0; nt < 2; ++nt)
                #pragma unroll
                for (int r = 0; r < 4; ++r)
                    Cb[(m0 + wm + mt * 16 + quad * 4 + r) * ldc + n0 + wn + nt * 16 + lrow] = acc[mt][nt][r];
    } else {
        ushort* Cb = (ushort*)C + (long)z * cZ;
        #pragma unroll
        for (int mt = 0; mt < 2; ++mt)
            #pragma unroll
            for (int nt = 0; nt < 2; ++nt)
                #pragma unroll
                for (int r = 0; r < 4; ++r)
                    Cb[(m0 + wm + mt * 16 + quad * 4 + r) * ldc + n0 + wn + nt * 16 + lrow] = f2bf(acc[mt][nt][r]);
    }
}

// ---------------------------------------------------------------- GEMM 128-tile, global_load_lds (m97-class)
// Tile M=N=128, BK=64. LDS unpadded (global_load_lds requires contiguous lane order).
// 4 waves in 2x2 quadrants of 64x64; 4x4 16x16x32 frags each.
__global__ __launch_bounds__(256, 2) void gemm_bt128(
    const ushort* __restrict__ A, const ushort* __restrict__ Bt,
    void* __restrict__ C, int K, int lda, int ldb, int ldc,
    long aZ, long bZ, long cZ, int c_f32) {
    __shared__ __align__(16) ushort As[128 * 64];
    __shared__ __align__(16) ushort Bs[128 * 64];
    const int z = blockIdx.z;
    const ushort* Ab = A + (long)z * aZ;
    const ushort* Bb = Bt + (long)z * bZ;
    const long m0 = (long)blockIdx.y * 128;
    const long n0 = (long)blockIdx.x * 128;
    const int tid = threadIdx.x;
    const int lane = tid & 63, w = tid >> 6;
    const int wm = (w >> 1) * 64, wn = (w & 1) * 64;
    const int lrow = lane & 15, quad = lane >> 4;

    floatx4 acc[4][4] = {};

    for (int k0 = 0; k0 < K; k0 += 64) {
        __syncthreads();  // prev-iter LDS reads done before overwrite
        #pragma unroll
        for (int t = 0; t < 4; ++t) {
            const int c = t * 256 + tid;          // chunk id: lds dest = base + lane*16
            const int r = c >> 3, kc = (c & 7) * 8;
            __builtin_amdgcn_global_load_lds(
                (const __attribute__((address_space(1))) unsigned int*)(Ab + (m0 + r) * lda + k0 + kc),
                (__attribute__((address_space(3))) unsigned int*)(As + (long)c * 8), 16, 0, 0);
            __builtin_amdgcn_global_load_lds(
                (const __attribute__((address_space(1))) unsigned int*)(Bb + (n0 + r) * ldb + k0 + kc),
                (__attribute__((address_space(3))) unsigned int*)(Bs + (long)c * 8), 16, 0, 0);
        }
        __syncthreads();  // drains vmcnt -> staged tile visible
        #pragma unroll
        for (int kk = 0; kk < 64; kk += 32) {
            bf16x8 af[4], bv[4];
            #pragma unroll
            for (int i = 0; i < 4; ++i) {
                af[i] = ldb8(&As[(wm + i * 16 + lrow) * 64 + kk + quad * 8]);
                bv[i] = ldb8(&Bs[(wn + i * 16 + lrow) * 64 + kk + quad * 8]);
            }
            #pragma unroll
            for (int i = 0; i < 4; ++i)
                #pragma unroll
                for (int j = 0; j < 4; ++j)
                    acc[i][j] = MFMA(af[i], bv[j], acc[i][j]);
        }
    }
    if (c_f32) {
        float* Cb = (float*)C + (long)z * cZ;
        #pragma unroll
        for (int mt = 0; mt < 4; ++mt)
            #pragma unroll
            for (int nt = 0; nt < 4; ++nt)
                #pragma unroll
                for (int r = 0; r < 4; ++r)
                    Cb[(m0 + wm + mt * 16 + quad * 4 + r) * ldc + n0 + wn + nt * 16 + lrow] = acc[mt][nt][r];
    } else {
        ushort* Cb = (ushort*)C + (long)z * cZ;
        #pragma unroll
        for (int mt = 0; mt < 4; ++mt)
            #pragma unroll
            for (int nt = 0; nt < 4; ++nt)
                #pragma unroll
                for (int r = 0; r < 4; ++r)
                    Cb[(m0 + wm + mt * 16 + quad * 4 + r) * ldc + n0 + wn + nt * 16 + lrow] = f2bf(acc[mt][nt][r]);
    }
}

// ---------------------------------------------------------------- RMSNorm D=1536 (supports in==out; w is fp32)
__global__ __launch_bounds__(256) void rms1536(
    const ushort* in, const float* __restrict__ w, ushort* out) {
    const int row = blockIdx.x, t = threadIdx.x;
    const ushort* ip = in + (long)row * 1536;
    float v[6]; float ss = 0.f;
    #pragma unroll
    for (int i = 0; i < 6; ++i) { v[i] = bf2f(ip[i * 256 + t]); ss += v[i] * v[i]; }
    __shared__ float red[256];
    red[t] = ss; __syncthreads();
    for (int st = 128; st > 0; st >>= 1) { if (t < st) red[t] += red[t + st]; __syncthreads(); }
    const float sc = rsqrtf(red[0] * (1.f / 1536.f) + 1e-6f);
    ushort* op = out + (long)row * 1536;
    #pragma unroll
    for (int i = 0; i < 6; ++i) op[i * 256 + t] = f2bf(v[i] * sc * w[i * 256 + t]);
}

// ---------------------------------------------------------------- q RoPE
__global__ __launch_bounds__(256) void qrope(
    const ushort* __restrict__ q, const float* __restrict__ freqs,
    ushort* __restrict__ qpe) {
    const int tok = blockIdx.x;
    const int s = tok & 2047;
    const int t = threadIdx.x;
    #pragma unroll
    for (int p = 0; p < 2; ++p) {
        const int idx = p * 256 + t;
        const int h = idx >> 5, i = idx & 31;
        const long base = (long)tok * 3072 + h * 192 + 128 + 2 * i;
        float x0 = bf2f(q[base]), x1 = bf2f(q[base + 1]);
        float th = freqs[s * 32 + i];
        float sn = sinf(th), cs = cosf(th);
        const long ob = (long)tok * 1024 + h * 64 + 2 * i;
        qpe[ob]     = f2bf(x0 * cs - x1 * sn);
        qpe[ob + 1] = f2bf(x0 * sn + x1 * cs);
    }
}

// ---------------------------------------------------------------- kv prep
__global__ __launch_bounds__(256) void kvprep(
    const ushort* __restrict__ kv, const float* __restrict__ w,
    const float* __restrict__ freqs, ushort* __restrict__ kvc,
    ushort* __restrict__ kvcT, ushort* __restrict__ kpe) {
    const int tok = blockIdx.x;
    const int b = tok >> 11, s = tok & 2047;
    const int t = threadIdx.x;
    const float v0 = bf2f(kv[(long)tok * 576 + t]);
    const float v1 = bf2f(kv[(long)tok * 576 + 256 + t]);
    __shared__ float red[256];
    red[t] = v0 * v0 + v1 * v1; __syncthreads();
    for (int st = 128; st > 0; st >>= 1) { if (t < st) red[t] += red[t + st]; __syncthreads(); }
    const float sc = rsqrtf(red[0] * (1.f / 512.f) + 1e-6f);
    const float y0 = v0 * sc * w[t];
    const float y1 = v1 * sc * w[256 + t];
    kvc[(long)tok * 512 + t] = f2bf(y0);
    kvc[(long)tok * 512 + 256 + t] = f2bf(y1);
    kvcT[(long)b * 1048576 + (long)t * 2048 + s] = f2bf(y0);
    kvcT[(long)b * 1048576 + (long)(256 + t) * 2048 + s] = f2bf(y1);
    if (t < 32) {
        float x0 = bf2f(kv[(long)tok * 576 + 512 + 2 * t]);
        float x1 = bf2f(kv[(long)tok * 576 + 512 + 2 * t + 1]);
        float th = freqs[s * 32 + t];
        float sn = sinf(th), cs = cosf(th);
        kpe[(long)tok * 64 + 2 * t]     = f2bf(x0 * cs - x1 * sn);
        kpe[(long)tok * 64 + 2 * t + 1] = f2bf(x0 * sn + x1 * cs);
    }
}

// ---------------------------------------------------------------- flash attention v3
// Grid (16, 16, 2): block handles q-tiles {qx, 31-qx} (66 kv-iters each -> perfect balance).
// v3 deltas vs v2: (a) staging map = consecutive lanes -> consecutive 16B chunks
// (kills the 8-way same-bank-group write conflict; also 128B-contiguous global reads);
// (b) alpha-rescale gated on __any(alpha != 1) (exact identity when max unchanged).
__global__ __launch_bounds__(256, 2) void mla_attn3(
    ushort* __restrict__ qo,           // in: q_abs (4096,16,512); out: O (same)
    const ushort* __restrict__ q_pe,   // (4096,16,64)
    const ushort* __restrict__ kvc,    // (4096,512)
    const ushort* __restrict__ kvcT,   // (2,512,2048)
    const ushort* __restrict__ kpe) {  // (4096,64)
    __shared__ __align__(16) ushort Ks[32][520];
    __shared__ __align__(16) ushort P[64][72];  // cols 64-65: alpha(f32), 66-67: l(f32)
    const int qx = blockIdx.x, h = blockIdx.y, b = blockIdx.z;
    const int tid = threadIdx.x, lane = tid & 63, w = tid >> 6;
    const int lrow = lane & 15, quad = lane >> 4;
    const long bb = (long)b * 2048;
    const float scale = 0.07216878364870323f;  // 192^-0.5
    const int srow = tid >> 3, scol = (tid & 7) * 8;  // staging: lanes -> consecutive 16B chunks

    for (int half = 0; half < 2; ++half) {
        const int qt = half ? (31 - qx) : qx;
        const int qrow = qt * 64;
        const long tokb = bb + qrow;

        bf16x8 qa[18];
        {
            const ushort* qp_ = qo + (tokb + w * 16 + lrow) * 8192 + h * 512 + quad * 8;
            #pragma unroll
            for (int ks = 0; ks < 16; ++ks) qa[ks] = ldb8(qp_ + ks * 32);
            const ushort* qq = q_pe + (tokb + w * 16 + lrow) * 1024 + h * 64 + quad * 8;
            qa[16] = ldb8(qq); qa[17] = ldb8(qq + 32);
        }

        floatx4 oacc[4][8] = {};        // [m-frag][v-frag]
        float m_i[4], l_i[4];
        #pragma unroll
        for (int r = 0; r < 4; ++r) { m_i[r] = -1e30f; l_i[r] = 0.f; }

        const int niter = (qt + 1) * 2;
        for (int t = 0; t < niter; ++t) {
            const int kv0 = t * 32;
            // ---- stage K-tile (32 x 512) into LDS ----
            {
                const ushort* src = kvc + (bb + kv0 + srow) * 512 + scol;
                #pragma unroll
                for (int j = 0; j < 8; ++j) {
                    uint4 v = *(const uint4*)(src + j * 64);
                    *(uint4*)&Ks[srow][scol + j * 64] = v;
                }
            }
            __syncthreads();  // A: stage visible; prev-iter PV done

            // ---- QK^T ----
            floatx4 sacc[2] = {};
            const ushort* pb0 = kpe + (bb + kv0 + lrow) * 64 + quad * 8;
            const ushort* pb1 = kpe + (bb + kv0 + 16 + lrow) * 64 + quad * 8;
            bf16x8 kp00 = ldb8(pb0), kp01 = ldb8(pb0 + 32);
            bf16x8 kp10 = ldb8(pb1), kp11 = ldb8(pb1 + 32);
            #pragma unroll
            for (int ks = 0; ks < 16; ++ks) {
                bf16x8 b0 = ldb8(&Ks[lrow][ks * 32 + quad * 8]);
                bf16x8 b1 = ldb8(&Ks[16 + lrow][ks * 32 + quad * 8]);
                sacc[0] = MFMA(qa[ks], b0, sacc[0]);
                sacc[1] = MFMA(qa[ks], b1, sacc[1]);
            }
            sacc[0] = MFMA(qa[16], kp00, sacc[0]);
            sacc[0] = MFMA(qa[17], kp01, sacc[0]);
            sacc[1] = MFMA(qa[16], kp10, sacc[1]);
            sacc[1] = MFMA(qa[17], kp11, sacc[1]);

            // ---- prefetch V b-frags ----
            bf16x8 vf[8];
            {
                const ushort* vb = kvcT + (long)b * 1048576 + (long)(w * 128 + lrow) * 2048 + kv0 + quad * 8;
                #pragma unroll
                for (int nf = 0; nf < 8; ++nf) vf[nf] = ldb8(vb + (long)nf * 16 * 2048);
            }

            // ---- online softmax ----
            #pragma unroll
            for (int r = 0; r < 4; ++r) {
                const int rloc = w * 16 + quad * 4 + r;
                const int row_s = qrow + rloc;
                float pv0 = sacc[0][r] * scale;
                float pv1 = sacc[1][r] * scale;
                if (kv0 + lrow > row_s)      pv0 = -1e30f;
                if (kv0 + 16 + lrow > row_s) pv1 = -1e30f;
                float smax = fmaxf(pv0, pv1);
                #pragma unroll
                for (int off = 1; off < 16; off <<= 1)
                    smax = fmaxf(smax, __shfl_xor(smax, off));
                const float mnew = fmaxf(m_i[r], smax);
                const float alpha = __expf(m_i[r] - mnew);
                float p0 = __expf(pv0 - mnew);
                float p1 = __expf(pv1 - mnew);
                P[rloc][lrow]      = f2bf(p0);
                P[rloc][16 + lrow] = f2bf(p1);
                float ps = p0 + p1;
                #pragma unroll
                for (int off = 1; off < 16; off <<= 1)
                    ps += __shfl_xor(ps, off);
                l_i[r] = l_i[r] * alpha + ps;
                m_i[r] = mnew;
                if (lrow == 0) *(float*)&P[rloc][64] = alpha;
            }
            __syncthreads();  // B: P + alpha visible

            // ---- PV: wave w owns v-slice [w*128,+128), all 64 q-rows ----
            #pragma unroll
            for (int mf = 0; mf < 4; ++mf) {
                float al[4];
                #pragma unroll
                for (int r = 0; r < 4; ++r) al[r] = *(const float*)&P[mf * 16 + quad * 4 + r][64];
                const int need = (al[0] != 1.f) | (al[1] != 1.f) | (al[2] != 1.f) | (al[3] != 1.f);
                if (__any(need)) {
                    #pragma unroll
                    for (int nf = 0; nf < 8; ++nf)
                        #pragma unroll
                        for (int r = 0; r < 4; ++r) oacc[mf][nf][r] *= al[r];
                }
                bf16x8 pf = ldb8(&P[mf * 16 + lrow][quad * 8]);
                #pragma unroll
                for (int nf = 0; nf < 8; ++nf)
                    oacc[mf][nf] = MFMA(pf, vf[nf], oacc[mf][nf]);
            }
        }

        // ---- epilogue ----
        {
            #pragma unroll
            for (int r = 0; r < 4; ++r)
                if (lrow == 0) *(float*)&P[w * 16 + quad * 4 + r][66] = l_i[r];
        }
        __syncthreads();
        #pragma unroll
        for (int mf = 0; mf < 4; ++mf) {
            float li[4];
            #pragma unroll
            for (int r = 0; r < 4; ++r) li[r] = *(const float*)&P[mf * 16 + quad * 4 + r][66];
            #pragma unroll
            for (int nf = 0; nf < 8; ++nf)
                #pragma unroll
                for (int r = 0; r < 4; ++r) {
                    long tok = tokb + mf * 16 + quad * 4 + r;
                    qo[tok * 8192 + h * 512 + w * 128 + nf * 16 + lrow] = f2bf(oacc[mf][nf][r] / li[r]);
                }
        }
        __syncthreads();  // protect P/Ks before next half
    }
}

// ---------------------------------------------------------------- launcher
extern "C" void kernel_launch(void* const* d_in, const int* in_sizes, int n_in,
                              void* d_out, int out_size, void* d_ws, size_t ws_size,
                              hipStream_t stream) {
    const float* x      = (const float*)d_in[0];
    const float* freqs  = (const float*)d_in[1];
    const float* wq_a   = (const float*)d_in[3];
    const float* qnw    = (const float*)d_in[4];
    const float* wq_b   = (const float*)d_in[5];
    const float* wkv_a  = (const float*)d_in[6];
    const float* kvnw   = (const float*)d_in[7];
    const float* wkv_b  = (const float*)d_in[8];
    const float* wo     = (const float*)d_in[9];
    float* out = (float*)d_out;
    (void)ws_size; (void)in_sizes; (void)n_in; (void)out_size;

    char* ws = (char*)d_ws;
    ushort* q_abs  = (ushort*)(ws + 0);
    ushort* q_lat  = (ushort*)(ws + 0);
    ushort* kv     = (ushort*)(ws + 12582912);
    ushort* xb     = (ushort*)(ws + 17301504);
    ushort* wq_aT  = (ushort*)(ws + 34078720);
    ushort* wq_bT  = (ushort*)(ws + 40370176);
    ushort* wkv_aT = (ushort*)(ws + 49807360);
    ushort* q      = (ushort*)(ws + 67108864);
    ushort* o2     = (ushort*)(ws + 67108864);
    ushort* qpe    = (ushort*)(ws + 92274688);
    ushort* kvc    = (ushort*)(ws + 100663296);
    ushort* kvcT   = (ushort*)(ws + 104857600);
    ushort* kpe    = (ushort*)(ws + 109051904);
    ushort* wkv_bC = (ushort*)(ws + 109576192);
    ushort* wkv_bT = (ushort*)(ws + 113770496);
    ushort* woT    = (ushort*)(ws + 117964800);

    dim3 tb(32, 8);
    transpose_f32_bf16<<<dim3(48, 64), tb, 0, stream>>>(wq_a, wq_aT, 2048, 1536);
    transpose_f32_bf16<<<dim3(96, 48), tb, 0, stream>>>(wq_b, wq_bT, 1536, 3072);
    transpose_f32_bf16<<<dim3(18, 64), tb, 0, stream>>>(wkv_a, wkv_aT, 2048, 576);
    transpose_f32_bf16<<<dim3(128, 16), tb, 0, stream>>>(wkv_b, wkv_bT, 512, 4096);
    transpose_f32_bf16<<<dim3(64, 64), tb, 0, stream>>>(wo, woT, 2048, 2048);
    cvt_f32_bf16<<<8192, 256, 0, stream>>>(x, xb, 8388608L);
    cvt_f32_bf16<<<2048, 256, 0, stream>>>(wkv_b, wkv_bC, 2097152L);

    // q_lat = x @ wq_a            (4096 x 1536, K=2048)
    gemm_bt128<<<dim3(12, 32, 1), 256, 0, stream>>>(xb, wq_aT, q_lat, 2048, 2048, 2048, 1536, 0, 0, 0, 0);
    // qn = rmsnorm(q_lat) (in place)
    rms1536<<<4096, 256, 0, stream>>>(q_lat, qnw, q_lat);
    // q = qn @ wq_b               (4096 x 3072, K=1536)
    gemm_bt128<<<dim3(24, 32, 1), 256, 0, stream>>>(q_lat, wq_bT, q, 1536, 1536, 1536, 3072, 0, 0, 0, 0);
    // q_pe = rope(q[..., 128:192])
    qrope<<<4096, 256, 0, stream>>>(q, freqs, qpe);
    // kv = x @ wkv_a              (4096 x 576, K=2048) — N=576 not /128, keep 64-tile
    gemm_bt<<<dim3(9, 64, 1), 256, 0, stream>>>(xb, wkv_aT, kv, 2048, 2048, 2048, 576, 0, 0, 0, 0);
    // kvc / kvcT / kpe
    kvprep<<<4096, 256, 0, stream>>>(kv, kvnw, freqs, kvc, kvcT, kpe);
    // q_abs[h] = q_nope[h] @ wkv_b_mat[h,:128]^T   (N=512 per head -> grid.x = 512/128 = 4)
    gemm_bt128<<<dim3(4, 32, 16), 256, 0, stream>>>(q, wkv_bC, q_abs, 128, 3072, 4096, 8192, 192, 256, 512, 0);
    // flash attention; O overwrites q_abs in place
    mla_attn3<<<dim3(16, 16, 2), 256, 0, stream>>>(q_abs, qpe, kvc, kvcT, kpe);
    // o2[h] = o[h] @ wkv_b_mat[h,128:]   (N=128 per head)
    gemm_bt128<<<dim3(1, 32, 16), 256, 0, stream>>>(q_abs, wkv_bT + 128L * 512, o2, 512, 8192, 512, 2048, 512, 131072, 128, 0);
    // out = o2 @ wo (fp32 output)
    gemm_bt128<<<dim3(16, 32, 1), 256, 0, stream>>>(o2, woT, out, 2048, 2048, 2048, 2048, 0, 0, 0, 1);
}